// Round 9
// baseline (261.576 us; speedup 1.0000x reference)
//
#include <hip/hip_runtime.h>
#include <hip/hip_fp16.h>

// GraphConv on MI355X — round 9: occupancy via work-split.
// K1: grid 2048 = (b, rg, sender-half): 8 receivers x 32 senders per block.
//     LDS 13.3 KB, __launch_bounds__(256,6) -> target 24 waves/CU (1.5x R7).
//     One barrier. Partial msg sums -> d_ws (per-half slots, no atomics).
// K2: grid 512 x 64 thr: sum halves + decoder via MFMA (16 nodes/block).
// R8 lesson: LDS weight staging + extra barriers regressed; scalar L2-hot
// weight loads (R7 style) kept.

typedef _Float16 hf;
typedef __attribute__((ext_vector_type(8))) _Float16 v8hf;  // 4 VGPRs, MFMA A/B
typedef __attribute__((ext_vector_type(4))) float fv4;      // MFMA accumulator

union ABh { v8hf v; __half2 h[4]; };

// ---------------- K1 ----------------
__global__ __launch_bounds__(256, 6) void k1_msg(
    const float* __restrict__ ns, const float* __restrict__ et,
    const float* __restrict__ e0w1, const float* __restrict__ e0b1,
    const float* __restrict__ e0w2, const float* __restrict__ e0b2,
    const float* __restrict__ e1w1, const float* __restrict__ e1b1,
    const float* __restrict__ e1w2, const float* __restrict__ e1b2,
    float* __restrict__ wsmsg)            // [sh][b][r][h] fp32, 4 MB
{
  __shared__ __align__(16) _Float16 PlH[2*32*72];  // 9216 B  P (this sender half)
  __shared__ __align__(16) _Float16 QbH[2*8*64];   // 2048 B  Q + b1
  __shared__ float ETl[2*8*32];                    // 2048 B  edge weights
                                                   // total 13312 B

  int t = threadIdx.x;
  int bid = blockIdx.x;
  int b = bid >> 4, rg = (bid >> 1) & 7, sh = bid & 1;
  int r0 = rg*8, s0 = sh*32;
  int w = t >> 6, lane = t & 63, quad = lane >> 4, col = lane & 15;

  const __half2 z2 = __float22half2_rn(make_float2(0.f, 0.f));
  const v8hf zero8 = {};

  // ---- et gather: one (rl, s_local) pair per thread ----
  {
    int sl = t >> 3, rl = t & 7;
    int s = s0 + sl, r = r0 + rl;
    float v0 = 0.f, v1 = 0.f;
    if (s != r) {
      int pos = r - (r > s ? 1 : 0);
      const float* base = et + (b*4032 + s*63 + pos)*3;
      v0 = base[1]; v1 = base[2];
    }
    ETl[rl*32 + sl] = v0;
    ETl[256 + rl*32 + sl] = v1;
  }

  // ---- phase 1: P/Q via MFMA, wave-specialized (2 tasks per wave) ----
  // wave1: P tile st=0 (senders s0..s0+15), both enc
  // wave3: P tile st=1 (senders s0+16..s0+31), both enc
  // wave0: Q enc0, wave2: Q enc1 (receivers r0..r0+7, rows 8-15 junk-valid)
  {
    int nsrow = (w == 1) ? (s0 + col)
              : (w == 3) ? (s0 + 16 + col)
              : min(r0 + col, 63);
    ABh a;
    if (quad < 2) {
      const float* xr = ns + (b*64 + nsrow)*16 + quad*8;
      float4 x0 = *(const float4*)xr;
      float4 x1 = *(const float4*)(xr + 4);
      a.h[0] = __float22half2_rn(make_float2(x0.x, x0.y));
      a.h[1] = __float22half2_rn(make_float2(x0.z, x0.w));
      a.h[2] = __float22half2_rn(make_float2(x1.x, x1.y));
      a.h[3] = __float22half2_rn(make_float2(x1.z, x1.w));
    } else {
      a.h[0] = a.h[1] = a.h[2] = a.h[3] = z2;
    }
    if (w & 1) {                          // P waves
      int st = (w == 3);
#pragma unroll 1
      for (int enc = 0; enc < 2; ++enc) {
        const float* w1 = enc ? e1w1 : e0w1;
#pragma unroll
        for (int ht = 0; ht < 4; ++ht) {
          int cc = ht*16 + col;
          ABh bb;
          if (quad < 2) {
#pragma unroll
            for (int j = 0; j < 4; ++j) {
              float f0 = w1[(quad*8 + 2*j    )*64 + cc];
              float f1 = w1[(quad*8 + 2*j + 1)*64 + cc];
              bb.h[j] = __float22half2_rn(make_float2(f0, f1));
            }
          } else {
            bb.h[0] = bb.h[1] = bb.h[2] = bb.h[3] = z2;
          }
          fv4 acc = {0.f, 0.f, 0.f, 0.f};
          acc = __builtin_amdgcn_mfma_f32_16x16x32_f16(a.v, bb.v, acc, 0, 0, 0);
          hf* pd = PlH + enc*2304 + (st*16 + quad*4)*72 + cc;
          pd[0*72] = (hf)acc[0];
          pd[1*72] = (hf)acc[1];
          pd[2*72] = (hf)acc[2];
          pd[3*72] = (hf)acc[3];
        }
      }
    } else {                              // Q waves
      int enc = (w == 2);
      const float* w1 = enc ? e1w1 : e0w1;
      const float* b1 = enc ? e1b1 : e0b1;
#pragma unroll
      for (int ht = 0; ht < 4; ++ht) {
        int cc = ht*16 + col;
        ABh bb;
        if (quad < 2) {
#pragma unroll
          for (int j = 0; j < 4; ++j) {
            float f0 = w1[(16 + quad*8 + 2*j    )*64 + cc];
            float f1 = w1[(16 + quad*8 + 2*j + 1)*64 + cc];
            bb.h[j] = __float22half2_rn(make_float2(f0, f1));
          }
        } else {
          bb.h[0] = bb.h[1] = bb.h[2] = bb.h[3] = z2;
        }
        fv4 acc = {0.f, 0.f, 0.f, 0.f};
        acc = __builtin_amdgcn_mfma_f32_16x16x32_f16(a.v, bb.v, acc, 0, 0, 0);
        float b1v = b1[cc];
        if (quad < 2) {                   // C rows 0..7 = receivers
#pragma unroll
          for (int rr = 0; rr < 4; ++rr)
            QbH[enc*512 + (quad*4 + rr)*64 + cc] = (hf)(acc[rr] + b1v);
        }
      }
    }
  }
  __syncthreads();                        // the only barrier

  // ---- main loop: h2 = relu(h1 @ W2 + b2), et-weighted sum over 32 senders
  float msgacc[2][4] = {{0.f,0.f,0.f,0.f},{0.f,0.f,0.f,0.f}};

#pragma unroll 1
  for (int enc = 0; enc < 2; ++enc) {
    const float* w2 = enc ? e1w2 : e0w2;
    const float* b2 = enc ? e1b2 : e0b2;
    v8hf bfr[4][2];
    float b2v[4];
#pragma unroll
    for (int nt = 0; nt < 4; ++nt) {
#pragma unroll
      for (int kk = 0; kk < 2; ++kk) {
        const float* base = w2 + (kk*32 + quad*8)*64 + nt*16 + col;
        ABh bb;
        bb.h[0] = __float22half2_rn(make_float2(base[0*64], base[1*64]));
        bb.h[1] = __float22half2_rn(make_float2(base[2*64], base[3*64]));
        bb.h[2] = __float22half2_rn(make_float2(base[4*64], base[5*64]));
        bb.h[3] = __float22half2_rn(make_float2(base[6*64], base[7*64]));
        bfr[nt][kk] = bb.v;
      }
      b2v[nt] = b2[nt*16 + col];
    }
#pragma unroll 1
    for (int rli = 0; rli < 2; ++rli) {
      int rl = w*2 + rli;
      const hf* qrow = QbH + enc*512 + rl*64;
      v8hf q0 = *(const v8hf*)(qrow + quad*8);
      v8hf q1 = *(const v8hf*)(qrow + 32 + quad*8);
      const float* etrow = ETl + enc*256 + rl*32;
#pragma unroll
      for (int st = 0; st < 2; ++st) {
        const hf* prow = PlH + enc*2304 + (st*16 + col)*72 + quad*8;
        v8hf p0 = *(const v8hf*)prow;
        v8hf p1 = *(const v8hf*)(prow + 32);
        v8hf sA = __builtin_elementwise_max(p0 + q0, zero8);
        v8hf sB = __builtin_elementwise_max(p1 + q1, zero8);
        float4 etv = *(const float4*)(etrow + st*16 + quad*4);
#pragma unroll
        for (int nt = 0; nt < 4; ++nt) {
          fv4 acc = {b2v[nt], b2v[nt], b2v[nt], b2v[nt]};
          acc = __builtin_amdgcn_mfma_f32_16x16x32_f16(sA, bfr[nt][0], acc, 0, 0, 0);
          acc = __builtin_amdgcn_mfma_f32_16x16x32_f16(sB, bfr[nt][1], acc, 0, 0, 0);
          float m = msgacc[rli][nt];
          m += etv.x * fmaxf(acc[0], 0.f);
          m += etv.y * fmaxf(acc[1], 0.f);
          m += etv.z * fmaxf(acc[2], 0.f);
          m += etv.w * fmaxf(acc[3], 0.f);
          msgacc[rli][nt] = m;
        }
      }
    }
  }
  // quad reduction over senders -> ws partial slot (no atomics)
#pragma unroll
  for (int rli = 0; rli < 2; ++rli) {
#pragma unroll
    for (int nt = 0; nt < 4; ++nt) {
      float v = msgacc[rli][nt];
      v += __shfl_xor(v, 16);
      v += __shfl_xor(v, 32);
      if (lane < 16) {
        int r = rg*8 + w*2 + rli;
        wsmsg[((sh*128 + b)*64 + r)*64 + nt*16 + lane] = v;
      }
    }
  }
}

// ---------------- K2: decoder ----------------
// grid 512 x 64 threads: block = (b, quarter), 16 nodes via MFMA.
__global__ __launch_bounds__(64) void k2_decode(
    const float* __restrict__ ns, const float* __restrict__ wsmsg,
    const float* __restrict__ ndw1, const float* __restrict__ ndb1,
    const float* __restrict__ ndw2, const float* __restrict__ ndb2,
    float* __restrict__ out)
{
  __shared__ __align__(16) _Float16 HD[16*72];     // 2304 B

  int t = threadIdx.x;
  int b = blockIdx.x >> 2, n0 = (blockIdx.x & 3)*16;
  int quad = t >> 4, col = t & 15;

  // A-frags: XD[m=col][k], k<16: ns; 16<=k<80: msg (ws half0 + half1); else 0
  ABh xa[3];
#pragma unroll
  for (int kk = 0; kk < 3; ++kk) {
    int k0 = kk*32 + quad*8;
    ABh a;
    if (k0 < 16) {
      const float* p = ns + (b*64 + n0 + col)*16 + k0;
      float4 u0 = *(const float4*)p, u1 = *(const float4*)(p + 4);
      a.h[0] = __float22half2_rn(make_float2(u0.x, u0.y));
      a.h[1] = __float22half2_rn(make_float2(u0.z, u0.w));
      a.h[2] = __float22half2_rn(make_float2(u1.x, u1.y));
      a.h[3] = __float22half2_rn(make_float2(u1.z, u1.w));
    } else if (k0 < 80) {
      int h = k0 - 16;
      const float* p0 = wsmsg + ((0*128 + b)*64 + n0 + col)*64 + h;
      const float* p1 = wsmsg + ((1*128 + b)*64 + n0 + col)*64 + h;
      float4 u0 = *(const float4*)p0, u1 = *(const float4*)(p0 + 4);
      float4 v0 = *(const float4*)p1, v1 = *(const float4*)(p1 + 4);
      a.h[0] = __float22half2_rn(make_float2(u0.x + v0.x, u0.y + v0.y));
      a.h[1] = __float22half2_rn(make_float2(u0.z + v0.z, u0.w + v0.w));
      a.h[2] = __float22half2_rn(make_float2(u1.x + v1.x, u1.y + v1.y));
      a.h[3] = __float22half2_rn(make_float2(u1.z + v1.z, u1.w + v1.w));
    } else {
      a.h[0] = a.h[1] = a.h[2] = a.h[3] = __float22half2_rn(make_float2(0.f, 0.f));
    }
    xa[kk] = a;
  }
  // layer1: HD[m][cc] = relu(XD @ ndw1 + b1)
#pragma unroll
  for (int ht = 0; ht < 4; ++ht) {
    int cc = ht*16 + col;
    float bias = ndb1[cc];
    fv4 acc = {bias, bias, bias, bias};
#pragma unroll
    for (int kk = 0; kk < 3; ++kk) {
      ABh bb;
#pragma unroll
      for (int j = 0; j < 4; ++j) {
        int rA = kk*32 + quad*8 + 2*j, rB = rA + 1;
        float f0 = (rA < 80) ? ndw1[rA*64 + cc] : 0.f;
        float f1 = (rB < 80) ? ndw1[rB*64 + cc] : 0.f;
        bb.h[j] = __float22half2_rn(make_float2(f0, f1));
      }
      acc = __builtin_amdgcn_mfma_f32_16x16x32_f16(xa[kk].v, bb.v, acc, 0, 0, 0);
    }
#pragma unroll
    for (int rr = 0; rr < 4; ++rr)
      HD[(quad*4 + rr)*72 + cc] = (hf)fmaxf(acc[rr], 0.f);
  }
  __syncthreads();   // single-wave block: cheap waitcnt+barrier

  // layer2: out = relu(HD @ ndw2 + b2)
  const hf* hrow = HD + col*72;
  v8hf ha0 = *(const v8hf*)(hrow + quad*8);
  v8hf ha1 = *(const v8hf*)(hrow + 32 + quad*8);
  ABh b20, b21;
#pragma unroll
  for (int j = 0; j < 4; ++j) {
    float f0 = ndw2[(quad*8 + 2*j    )*16 + col];
    float f1 = ndw2[(quad*8 + 2*j + 1)*16 + col];
    b20.h[j] = __float22half2_rn(make_float2(f0, f1));
    float g0 = ndw2[(32 + quad*8 + 2*j    )*16 + col];
    float g1 = ndw2[(32 + quad*8 + 2*j + 1)*16 + col];
    b21.h[j] = __float22half2_rn(make_float2(g0, g1));
  }
  float bias2 = ndb2[col];
  fv4 acc2 = {bias2, bias2, bias2, bias2};
  acc2 = __builtin_amdgcn_mfma_f32_16x16x32_f16(ha0, b20.v, acc2, 0, 0, 0);
  acc2 = __builtin_amdgcn_mfma_f32_16x16x32_f16(ha1, b21.v, acc2, 0, 0, 0);
#pragma unroll
  for (int rr = 0; rr < 4; ++rr) {
    int m = quad*4 + rr;
    out[(b*64 + n0 + m)*16 + col] = fmaxf(acc2[rr], 0.f);
  }
}

extern "C" void kernel_launch(void* const* d_in, const int* in_sizes, int n_in,
                              void* d_out, int out_size, void* d_ws, size_t ws_size,
                              hipStream_t stream) {
  const float* ns   = (const float*)d_in[0];
  const float* et   = (const float*)d_in[1];
  const float* e0w1 = (const float*)d_in[2];
  const float* e0b1 = (const float*)d_in[3];
  const float* e0w2 = (const float*)d_in[4];
  const float* e0b2 = (const float*)d_in[5];
  const float* e1w1 = (const float*)d_in[6];
  const float* e1b1 = (const float*)d_in[7];
  const float* e1w2 = (const float*)d_in[8];
  const float* e1b2 = (const float*)d_in[9];
  const float* ndw1 = (const float*)d_in[10];
  const float* ndb1 = (const float*)d_in[11];
  const float* ndw2 = (const float*)d_in[12];
  const float* ndb2 = (const float*)d_in[13];

  float* wsmsg = (float*)d_ws;            // 2 x 128 x 64 x 64 fp32 = 4 MB

  k1_msg<<<2048, 256, 0, stream>>>(ns, et,
                                   e0w1, e0b1, e0w2, e0b2,
                                   e1w1, e1b1, e1w2, e1b2,
                                   wsmsg);
  k2_decode<<<512, 64, 0, stream>>>(ns, wsmsg, ndw1, ndb1, ndw2, ndb2,
                                    (float*)d_out);
}

// Round 10
// 135.364 us; speedup vs baseline: 1.9324x; 1.9324x over previous
//
#include <hip/hip_runtime.h>
#include <hip/hip_fp16.h>

// GraphConv on MI355X — round 10 = round 7 + W2 B-frag prefetch.
// R9 lesson (and R2): min-waves clamp >=5 forces catastrophic spill; (256,4)
// is the spill-free ceiling -> 16 waves/CU is the TLP budget.
// Change vs R7: the W2 B-fragment build (64 scalar col-strided loads/thread
// per enc, previously exposed after barrier #1) is hoisted to kernel top for
// BOTH encoders; latency overlaps the P/Q MFMA prologue. +64 VGPR persistent,
// audited ~117 live < 128 cap. Tripwire: spill -> WRITE_SIZE balloon.

typedef _Float16 hf;
typedef __attribute__((ext_vector_type(8))) _Float16 v8hf;  // 4 VGPRs, MFMA A/B
typedef __attribute__((ext_vector_type(4))) float fv4;      // MFMA accumulator

union ABh { v8hf v; __half2 h[4]; };

// grid = 128 b * 8 recv-groups, 256 threads (4 waves).
__global__ __launch_bounds__(256, 4) void fused_kernel(
    const float* __restrict__ ns, const float* __restrict__ et,
    const float* __restrict__ e0w1, const float* __restrict__ e0b1,
    const float* __restrict__ e0w2, const float* __restrict__ e0b2,
    const float* __restrict__ e1w1, const float* __restrict__ e1b1,
    const float* __restrict__ e1w2, const float* __restrict__ e1b2,
    const float* __restrict__ ndw1, const float* __restrict__ ndb1,
    const float* __restrict__ ndw2, const float* __restrict__ ndb2,
    float* __restrict__ out)
{
  __shared__ __align__(16) _Float16 PlH[2*64*72];   // 18432 B  P partials
  __shared__ __align__(16) _Float16 QbH[2*8*64];    //  2048 B  Q + b1
  __shared__ float ETl[2*8*64];                     //  4096 B  edge weights
  // XDH: rows 0-7 = XD ([ns(16) | msg(64) | 0(16)] stride 104);
  //      rows 8-23 = HD2 (decoder hidden, 16 rows so garbage reads stay in-bounds)
  __shared__ __align__(16) _Float16 XDH[24*104];    //  4992 B
                                                    // total 29568 B
  _Float16* XD  = XDH;
  _Float16* HD2 = XDH + 8*104;

  int t = threadIdx.x;
  int b = blockIdx.x >> 3, rg = blockIdx.x & 7, r0 = rg*8;
  int w = t >> 6, lane = t & 63, quad = lane >> 4, col = lane & 15;

  const __half2 z2 = __float22half2_rn(make_float2(0.f, 0.f));
  const v8hf zero8 = {};

  // ======== early global loads (latency overlapped with P/Q MFMAs) ========
  float xnv = 0.f;
  if (t < 128) xnv = ns[(b*64 + r0 + (t >> 4))*16 + (t & 15)];
  float ev0[2], ev1[2];
#pragma unroll
  for (int i = 0; i < 2; ++i) {
    int idx = i*256 + t;                  // 0..511 -> (s, rl)
    int s = idx >> 3, rl = idx & 7;
    int r = r0 + rl;
    float v0 = 0.f, v1 = 0.f;
    if (s != r) {
      int pos = r - (r > s ? 1 : 0);
      const float* base = et + (b*4032 + s*63 + pos)*3;
      v0 = base[1]; v1 = base[2];
    }
    ev0[i] = v0; ev1[i] = v1;
  }

  // ======== W2 B-frags + b2, BOTH encoders, prefetched at kernel top ======
  // lane holds W2[k=kk*32+quad*8+j][n=nt*16+col]; consumed after barrier #1.
  v8hf bfr[2][4][2];
  float b2v[2][4];
#pragma unroll
  for (int enc = 0; enc < 2; ++enc) {
    const float* w2 = enc ? e1w2 : e0w2;
    const float* b2 = enc ? e1b2 : e0b2;
#pragma unroll
    for (int nt = 0; nt < 4; ++nt) {
#pragma unroll
      for (int kk = 0; kk < 2; ++kk) {
        const float* base = w2 + (kk*32 + quad*8)*64 + nt*16 + col;
        ABh bb;
        bb.h[0] = __float22half2_rn(make_float2(base[0*64], base[1*64]));
        bb.h[1] = __float22half2_rn(make_float2(base[2*64], base[3*64]));
        bb.h[2] = __float22half2_rn(make_float2(base[4*64], base[5*64]));
        bb.h[3] = __float22half2_rn(make_float2(base[6*64], base[7*64]));
        bfr[enc][nt][kk] = bb.v;
      }
      b2v[enc][nt] = b2[nt*16 + col];
    }
  }

  // ======== P and Q via MFMA: node-tile @ W1 (64x64x16, K padded to 32) ====
  // wave w owns nodes w*16..w*16+15. A[m=col][k=quad*8+j] = ns[node][k], k<16.
  {
    ABh a;
    if (quad < 2) {
      const float* xr = ns + (b*64 + w*16 + col)*16 + quad*8;
      float4 x0 = *(const float4*)xr;
      float4 x1 = *(const float4*)(xr + 4);
      a.h[0] = __float22half2_rn(make_float2(x0.x, x0.y));
      a.h[1] = __float22half2_rn(make_float2(x0.z, x0.w));
      a.h[2] = __float22half2_rn(make_float2(x1.x, x1.y));
      a.h[3] = __float22half2_rn(make_float2(x1.z, x1.w));
    } else {
      a.h[0] = a.h[1] = a.h[2] = a.h[3] = z2;
    }
    bool qwave = (w == (rg >> 1));        // this wave's tile contains r0..r0+7
#pragma unroll 1
    for (int enc = 0; enc < 2; ++enc) {
      const float* w1 = enc ? e1w1 : e0w1;
      const float* b1 = enc ? e1b1 : e0b1;
#pragma unroll
      for (int ht = 0; ht < 4; ++ht) {
        int cc = ht*16 + col;
        ABh bb;
        if (quad < 2) {
#pragma unroll
          for (int j = 0; j < 4; ++j) {
            float f0 = w1[(quad*8 + 2*j    )*64 + cc];
            float f1 = w1[(quad*8 + 2*j + 1)*64 + cc];
            bb.h[j] = __float22half2_rn(make_float2(f0, f1));
          }
        } else {
          bb.h[0] = bb.h[1] = bb.h[2] = bb.h[3] = z2;
        }
        fv4 acc = {0.f, 0.f, 0.f, 0.f};
        acc = __builtin_amdgcn_mfma_f32_16x16x32_f16(a.v, bb.v, acc, 0, 0, 0);
        hf* pd = PlH + enc*4608 + (w*16 + quad*4)*72 + cc;
        pd[0*72] = (hf)acc[0];
        pd[1*72] = (hf)acc[1];
        pd[2*72] = (hf)acc[2];
        pd[3*72] = (hf)acc[3];
      }
      if (qwave) {                        // Q tile: W1 bottom rows 16..31
#pragma unroll
        for (int ht = 0; ht < 4; ++ht) {
          int cc = ht*16 + col;
          ABh bb;
          if (quad < 2) {
#pragma unroll
            for (int j = 0; j < 4; ++j) {
              float f0 = w1[(16 + quad*8 + 2*j    )*64 + cc];
              float f1 = w1[(16 + quad*8 + 2*j + 1)*64 + cc];
              bb.h[j] = __float22half2_rn(make_float2(f0, f1));
            }
          } else {
            bb.h[0] = bb.h[1] = bb.h[2] = bb.h[3] = z2;
          }
          fv4 acc = {0.f, 0.f, 0.f, 0.f};
          acc = __builtin_amdgcn_mfma_f32_16x16x32_f16(a.v, bb.v, acc, 0, 0, 0);
          float b1v = b1[cc];
#pragma unroll
          for (int rr = 0; rr < 4; ++rr) {
            int local = quad*4 + rr;      // node = w*16 + local
            if ((local >> 3) == (rg & 1)) // rows r0..r0+7 of this tile
              QbH[enc*512 + (local & 7)*64 + cc] = (hf)(acc[rr] + b1v);
          }
        }
      }
    }
  }
  // ---- store staged globals to LDS ----
  if (t < 128) {
    int rl = t >> 4, k = t & 15;
    XD[rl*104 + k] = (hf)xnv;             // ns part
    XD[rl*104 + 80 + k] = (hf)0.f;        // zero pad cols 80..95
  }
#pragma unroll
  for (int i = 0; i < 2; ++i) {
    int idx = i*256 + t;
    int s = idx >> 3, rl = idx & 7;
    ETl[rl*64 + s] = ev0[i];
    ETl[512 + rl*64 + s] = ev1[i];
  }
  __syncthreads();                        // barrier #1

  // ======== main loop: h2 = relu(h1 @ W2 + b2), et-weighted sum ========
  float msgacc[2][4] = {{0.f,0.f,0.f,0.f},{0.f,0.f,0.f,0.f}};

#pragma unroll 1
  for (int enc = 0; enc < 2; ++enc) {
#pragma unroll 1
    for (int rli = 0; rli < 2; ++rli) {
      int rl = w*2 + rli;                 // this wave owns receivers 2w, 2w+1
      const hf* qrow = QbH + (enc*8 + rl)*64;
      v8hf q0 = *(const v8hf*)(qrow + quad*8);
      v8hf q1 = *(const v8hf*)(qrow + 32 + quad*8);
      const float* etrow = ETl + (enc*8 + rl)*64;
#pragma unroll 2
      for (int st = 0; st < 4; ++st) {
        const hf* prow = PlH + enc*4608 + (st*16 + col)*72 + quad*8;
        v8hf p0 = *(const v8hf*)prow;
        v8hf p1 = *(const v8hf*)(prow + 32);
        v8hf s0 = __builtin_elementwise_max(p0 + q0, zero8);
        v8hf s1 = __builtin_elementwise_max(p1 + q1, zero8);
        float4 etv = *(const float4*)(etrow + st*16 + quad*4);
#pragma unroll
        for (int nt = 0; nt < 4; ++nt) {
          float bv = b2v[enc][nt];
          fv4 acc = {bv, bv, bv, bv};
          acc = __builtin_amdgcn_mfma_f32_16x16x32_f16(s0, bfr[enc][nt][0], acc, 0, 0, 0);
          acc = __builtin_amdgcn_mfma_f32_16x16x32_f16(s1, bfr[enc][nt][1], acc, 0, 0, 0);
          float m = msgacc[rli][nt];
          m += etv.x * fmaxf(acc[0], 0.f);
          m += etv.y * fmaxf(acc[1], 0.f);
          m += etv.z * fmaxf(acc[2], 0.f);
          m += etv.w * fmaxf(acc[3], 0.f);
          msgacc[rli][nt] = m;
        }
      }
    }
  }
  // quad reduction over senders -> XD msg part (fp16)
#pragma unroll
  for (int rli = 0; rli < 2; ++rli) {
#pragma unroll
    for (int nt = 0; nt < 4; ++nt) {
      float v = msgacc[rli][nt];
      v += __shfl_xor(v, 16);
      v += __shfl_xor(v, 32);
      if (lane < 16) XD[(w*2 + rli)*104 + 16 + nt*16 + lane] = (hf)v;
    }
  }
  __syncthreads();                        // barrier #2

  // ======== decoder via MFMA, wave 0 only ========
  // layer1: C[m=rl][n] = XD(8x96) @ ndw1(96x64, rows>=80 zero), +b1, relu
  // layer2: C[m=rl][o] = HD2(8x64) @ ndw2(64x16), +b2, relu -> out
  if (w == 0) {
    ABh xa[3];
    const hf* xrow = XD + col*104;        // A row = receiver rl (rows 8-15 unused)
#pragma unroll
    for (int kk = 0; kk < 3; ++kk) xa[kk].v = *(const v8hf*)(xrow + kk*32 + quad*8);
#pragma unroll
    for (int ht = 0; ht < 4; ++ht) {
      int cc = ht*16 + col;
      float bias = ndb1[cc];
      fv4 acc = {bias, bias, bias, bias};
#pragma unroll
      for (int kk = 0; kk < 3; ++kk) {
        ABh bb;
#pragma unroll
        for (int j = 0; j < 4; ++j) {
          int rA = kk*32 + quad*8 + 2*j;
          int rB = rA + 1;
          float f0 = ndw1[(rA < 80 ? rA : 79)*64 + cc] * (rA < 80 ? 1.f : 0.f);
          float f1 = ndw1[(rB < 80 ? rB : 79)*64 + cc] * (rB < 80 ? 1.f : 0.f);
          bb.h[j] = __float22half2_rn(make_float2(f0, f1));
        }
        acc = __builtin_amdgcn_mfma_f32_16x16x32_f16(xa[kk].v, bb.v, acc, 0, 0, 0);
      }
      if (quad < 2) {
#pragma unroll
        for (int rr = 0; rr < 4; ++rr)
          HD2[(quad*4 + rr)*104 + cc] = (hf)fmaxf(acc[rr], 0.f);
      }
    }
    // layer2 (same-wave LDS write->read: program order, no barrier needed)
    const hf* hrow = HD2 + col*104;
    v8hf ha0 = *(const v8hf*)(hrow + quad*8);
    v8hf ha1 = *(const v8hf*)(hrow + 32 + quad*8);
    ABh b20, b21;
#pragma unroll
    for (int j = 0; j < 4; ++j) {
      float f0 = ndw2[(quad*8 + 2*j    )*16 + col];
      float f1 = ndw2[(quad*8 + 2*j + 1)*16 + col];
      b20.h[j] = __float22half2_rn(make_float2(f0, f1));
      float g0 = ndw2[(32 + quad*8 + 2*j    )*16 + col];
      float g1 = ndw2[(32 + quad*8 + 2*j + 1)*16 + col];
      b21.h[j] = __float22half2_rn(make_float2(g0, g1));
    }
    float bias2 = ndb2[col];
    fv4 acc2 = {bias2, bias2, bias2, bias2};
    acc2 = __builtin_amdgcn_mfma_f32_16x16x32_f16(ha0, b20.v, acc2, 0, 0, 0);
    acc2 = __builtin_amdgcn_mfma_f32_16x16x32_f16(ha1, b21.v, acc2, 0, 0, 0);
    if (quad < 2) {
#pragma unroll
      for (int rr = 0; rr < 4; ++rr) {
        int rl = quad*4 + rr;
        out[(b*64 + r0 + rl)*16 + col] = fmaxf(acc2[rr], 0.f);
      }
    }
  }
}

extern "C" void kernel_launch(void* const* d_in, const int* in_sizes, int n_in,
                              void* d_out, int out_size, void* d_ws, size_t ws_size,
                              hipStream_t stream) {
  const float* ns   = (const float*)d_in[0];
  const float* et   = (const float*)d_in[1];
  const float* e0w1 = (const float*)d_in[2];
  const float* e0b1 = (const float*)d_in[3];
  const float* e0w2 = (const float*)d_in[4];
  const float* e0b2 = (const float*)d_in[5];
  const float* e1w1 = (const float*)d_in[6];
  const float* e1b1 = (const float*)d_in[7];
  const float* e1w2 = (const float*)d_in[8];
  const float* e1b2 = (const float*)d_in[9];
  const float* ndw1 = (const float*)d_in[10];
  const float* ndb1 = (const float*)d_in[11];
  const float* ndw2 = (const float*)d_in[12];
  const float* ndb2 = (const float*)d_in[13];

  fused_kernel<<<1024, 256, 0, stream>>>(ns, et,
                                         e0w1, e0b1, e0w2, e0b2,
                                         e1w1, e1b1, e1w2, e1b2,
                                         ndw1, ndb1, ndw2, ndb2,
                                         (float*)d_out);
}